// Round 5
// baseline (35968.369 us; speedup 1.0000x reference)
//
#include <hip/hip_runtime.h>
#include <hip/hip_bf16.h>
#include <math.h>

#define NN 65536
#define MATD 131072L   // doubles per complex matrix (re plane + im plane)
#define MAT0 32768L    // header size in doubles

// ws header offsets (doubles)
#define SC_DT 0
#define SC_NUINV 3
#define SC_EXPM_S 4
#define SC_EXPM_SCALE 5
#define SC_NORMS2 6
#define SC_MU 7
// 8,9: n1,ninf of M ; 10,11: n1,ninf of M^-1 ; 12,13: n1,ninf of S ; 14: F^2 of S
#define W_UNIT_RE 64
#define W_UNIT_IM 320
#define W_C_RE 576
#define W_C_IM 832
#define W_LD_RE 1088
#define W_LD_IM 1344
#define W_SU 1600
#define W_SLOT 1856
#define W_SLOTU 2112        // 256 entries -> ends 2368
#define W_W 2432            // 256*33*2 doubles -> ends 19328
#define FLAGBASE 20480      // 1 double per inversion (<=96 inversions)
#define TRBASE 22528        // 96 doubles per inversion (2 per NS iter, <=48 iters)
#define NPOOL 256           // virtual pool capacity (every unit can be pooled)

// matrix slots
#define S_EW 0
#define S_NUW 1
#define S_LAT 2
#define S_T2 3
#define S_T3 4
#define S_T4 5
#define S_E1 6
#define S_E2 7
#define S_M 8
#define S_M2 9
#define S_Y 10
#define S_Y2 11
#define S_IY 12
#define S_X 13
#define S_X2 14
#define S_T 15
#define S_W 16
#define S_V 17
#define S_G 18
#define S_G2 19
#define PBASE 20            // S^k at PBASE+k-1, k=1..32 -> 20..51
#define POOL0 52            // physical pool: A at 52..52+K-1, B at 52+K..52+2K-1

#define PI_D 3.14159265358979323846

__device__ inline double ldin(const void* p, int i, int dt){
    if (dt == 0) return (double)__bfloat162float(((const __hip_bfloat16*)p)[i]);
    if (dt == 1) return (double)((const float*)p)[i];
    return ((const double*)p)[i];
}

// ---------------- init: zero header ----------------
__global__ __launch_bounds__(256) void k_init(double* ws){
    ws[blockIdx.x * 256 + threadIdx.x] = 0.0;   // grid 128 -> 32768
}

// ---------------- input dtype detection ----------------
__global__ __launch_bounds__(64) void k_detect(const void* x, double* ws){
    __shared__ int ok[3];
    int t = threadIdx.x;
    if (t < 3) ok[t] = 1;
    __syncthreads();
    const __hip_bfloat16* pb = (const __hip_bfloat16*)x;
    for (int k = t; k < 256; k += 64){
        float v = __bfloat162float(pb[k]);
        if (!(v > 0.40f && v < 1.60f)) ok[0] = 0;
    }
    const float* pf = (const float*)x;
    { float v = pf[t]; if (!(v > 0.40f && v < 1.60f)) ok[1] = 0; }
    const double* pd = (const double*)x;
    { double v = pd[t]; if (!(v > 0.40 && v < 1.60)) ok[2] = 0; }
    __syncthreads();
    if (t == 0) ws[SC_DT] = ok[0] ? 0.0 : (ok[1] ? 1.0 : 2.0);
}

// ---------------- small vector stage (1 block) ----------------
__global__ __launch_bounds__(256) void k_small(
    const void* xin, const void* Ar, const void* Ai,
    const void* cAr, const void* cAi,
    double* ws, float* out)
{
    __shared__ double xs[256], twc[256], tws[256], ur[256], ui[256], red[256];
    int t = threadIdx.x;
    int dt = (int)ws[SC_DT];
    double x = ldin(xin, t, dt);
    xs[t] = x;
    red[t] = log(x);
    double ang = -2.0 * PI_D * (double)t / 256.0;
    twc[t] = cos(ang); tws[t] = sin(ang);
    __syncthreads();
    for (int s = 128; s > 0; s >>= 1){ if (t < s) red[t] += red[t+s]; __syncthreads(); }
    double slog = red[0];
    __syncthreads();
    double dy = (t == 0) ? 0.0 : (x - xs[t-1]);
    double r = x * exp(-slog / 256.0);
    double unr = r * cos(dy), uni = r * sin(dy);
    ur[t] = unr; ui[t] = uni;
    ws[W_UNIT_RE + t] = unr; ws[W_UNIT_IM + t] = uni;
    __syncthreads();
    double fr = 0.0, fi = 0.0;
    for (int n = 0; n < 256; n++){
        int m = (t * n) & 255;
        double c = twc[m], s = tws[m];
        fr += ur[n]*c - ui[n]*s;
        fi += ur[n]*s + ui[n]*c;
    }
    red[t] = fr; __syncthreads();
    for (int s = 128; s > 0; s >>= 1){ if (t < s) red[t] += red[t+s]; __syncthreads(); }
    double sr = red[0]; __syncthreads();
    red[t] = fi; __syncthreads();
    for (int s = 128; s > 0; s >>= 1){ if (t < s) red[t] += red[t+s]; __syncthreads(); }
    double si = red[0];
    double den = sr*sr + si*si;
    double cr = (fr*sr + fi*si) / den, ci = (fi*sr - fr*si) / den;
    ws[W_C_RE + t] = cr; ws[W_C_IM + t] = ci;
    double ar = ldin(Ar, t, dt), ai = ldin(Ai, t, dt);
    double car = ldin(cAr, t, dt), cai = ldin(cAi, t, dt);
    double pr = ar*unr - ai*uni, pi = ar*uni + ai*unr;
    double qr = car*pr + cai*pi, qi = car*pi - cai*pr;
    out[t] = (float)(x + atan2(qi, qr));
    double ldr = 0.5 * log((qr*qr + qi*qi) / (unr*unr + uni*uni));
    double ldi = atan2(qi, qr) - atan2(uni, unr);
    ws[W_LD_RE + t] = ldr; ws[W_LD_IM + t] = ldi;
}

// ---------------- build Ew and new_uw (fp64 planes) ----------------
__global__ __launch_bounds__(256) void k_build_mats(
    const void* Ewr, const void* Ewi, const void* uwr, const void* uwi, double* ws)
{
    int ij = blockIdx.x * 256 + threadIdx.x;
    int i = ij >> 8, j = ij & 255;
    int dt = (int)ws[SC_DT];
    double* EW = ws + MAT0 + (size_t)S_EW * MATD;
    EW[ij] = ldin(Ewr, ij, dt); EW[NN + ij] = ldin(Ewi, ij, dt);
    double* U = ws + MAT0 + (size_t)S_NUW * MATD;
    if (i == 0){ U[ij] = ws[W_LD_RE + j]; U[NN + ij] = ws[W_LD_IM + j]; }
    else { int src = (i-1)*256 + j; U[ij] = ldin(uwr, src, dt); U[NN + ij] = ldin(uwi, src, dt); }
}

// ---------------- norms: ws[idx]=n1, ws[idx+1]=ninf, ws[SC_NUINV]=1/(n1*ninf) ----
__global__ __launch_bounds__(256) void k_norm1inf(const double* M, double* ws, int idx)
{
    __shared__ double cs[256], rs[256];
    int t = threadIdx.x;
    double c = 0.0, r = 0.0;
    for (int i = 0; i < 256; i++){
        c += fabs(M[i*256 + t]) + fabs(M[NN + i*256 + t]);
        r += fabs(M[t*256 + i]) + fabs(M[NN + t*256 + i]);
    }
    cs[t] = c; rs[t] = r; __syncthreads();
    for (int s = 128; s > 0; s >>= 1){
        if (t < s){ cs[t] = fmax(cs[t], cs[t+s]); rs[t] = fmax(rs[t], rs[t+s]); }
        __syncthreads();
    }
    if (t == 0){
        ws[idx] = cs[0]; ws[idx+1] = rs[0];
        ws[SC_NUINV] = 1.0 / (cs[0] * rs[0]);
    }
}

// Frobenius^2 -> ws[14]
__global__ __launch_bounds__(256) void k_fro(const double* M, double* ws)
{
    __shared__ double red[256];
    int t = threadIdx.x;
    double s = 0.0;
    for (int i = 0; i < 256; i++){
        double a = M[i*256 + t], b = M[NN + i*256 + t];
        s += a*a + b*b;
    }
    red[t] = s; __syncthreads();
    for (int k = 128; k > 0; k >>= 1){ if (t < k) red[t] += red[t+k]; __syncthreads(); }
    if (t == 0) ws[14] = red[0];
}

// rigorous sigma_max upper bound: min( sqrt(n1*ninf), ||S||_F )
__global__ void k_snorm(double* ws)
{
    double b1 = sqrt(ws[12] * ws[13]);
    double b2 = sqrt(ws[14]);
    ws[SC_NORMS2] = fmin(b1, b2);
}

// X0 = conj(M)^T * (1/(n1*ninf))
__global__ __launch_bounds__(256) void k_txconj(double* ws, int dst, int src)
{
    int ij = blockIdx.x * 256 + threadIdx.x;
    int i = ij >> 8, j = ij & 255;
    double nu = ws[SC_NUINV];
    double* X = ws + MAT0 + (size_t)dst * MATD;
    const double* M = ws + MAT0 + (size_t)src * MATD;
    X[ij]      =  M[j*256 + i] * nu;
    X[NN + ij] = -M[NN + j*256 + i] * nu;
}

// ---------------- complex GEMM ----------------
// C = alpha*preA(A)*preB(B) + beta*D + gamma*I
// preA: 0 none, 1 conj, 2 (A-I).  preB: 0 none, 1 (2I-B).
// fm: 0 normal; 1 expm-squaring (round>ws[SC_EXPM_S] -> copy A); 2 NS T-step
// (skip if flag; accumulate trace); 3 NS X-step (latch flag from trace; skip->copy A)
__global__ __launch_bounds__(256) void k_zgemm(
    const double* __restrict__ Ab, const double* __restrict__ Bb,
    double* __restrict__ Cb, const double* __restrict__ Db,
    int preA, int preB, double alpha, double beta, double gamma,
    double* __restrict__ ws, int fm, int round, int flagIdx, int trIdx,
    long sA, long sB, long sC)
{
    int z = blockIdx.z;
    const double* A = Ab + (size_t)z * sA;
    const double* B = Bb + (size_t)z * sB;
    double* C = Cb + (size_t)z * sC;
    int tx = threadIdx.x & 15, ty = threadIdx.x >> 4;
    int row = blockIdx.y * 16 + ty, col = blockIdx.x * 16 + tx;
    if (fm == 1 && round > (int)ws[SC_EXPM_S]){
        C[row*256 + col] = A[row*256 + col];
        C[NN + row*256 + col] = A[NN + row*256 + col];
        return;
    }
    if (fm == 2){
        if (ws[flagIdx] != 0.0) return;
    }
    if (fm == 3){
        double fl = ws[flagIdx];
        if (blockIdx.x == 0 && blockIdx.y == 0 && threadIdx.x == 0 && fl == 0.0){
            double resid = fabs(256.0 - ws[trIdx]) + fabs(ws[trIdx+1]);
            if (resid < 2.56e-8) ws[flagIdx] = 1.0;
        }
        if (fl != 0.0){
            C[row*256 + col] = A[row*256 + col];
            C[NN + row*256 + col] = A[NN + row*256 + col];
            return;
        }
    }
    __shared__ double Asr[16][17], Asi[16][17], Bsr[16][17], Bsi[16][17];
    double cr = 0.0, ci = 0.0;
    for (int k0 = 0; k0 < 256; k0 += 16){
        int ac = k0 + tx;
        double a_re = A[row*256 + ac], a_im = A[NN + row*256 + ac];
        if (preA == 1) a_im = -a_im;
        else if (preA == 2){ if (row == ac) a_re -= 1.0; }
        int br = k0 + ty;
        double b_re = B[br*256 + col], b_im = B[NN + br*256 + col];
        if (preB == 1){ b_re = ((br == col) ? 2.0 : 0.0) - b_re; b_im = -b_im; }
        Asr[ty][tx] = a_re; Asi[ty][tx] = a_im;
        Bsr[ty][tx] = b_re; Bsi[ty][tx] = b_im;
        __syncthreads();
        #pragma unroll
        for (int kk = 0; kk < 16; kk++){
            double xr = Asr[ty][kk], xi = Asi[ty][kk];
            double yr = Bsr[kk][tx], yi = Bsi[kk][tx];
            cr += xr*yr - xi*yi;
            ci += xr*yi + xi*yr;
        }
        __syncthreads();
    }
    double outr = alpha * cr, outi = alpha * ci;
    if (Db){ outr += beta * Db[row*256 + col]; outi += beta * Db[NN + row*256 + col]; }
    if (row == col) outr += gamma;
    C[row*256 + col] = outr;
    C[NN + row*256 + col] = outi;
    if (fm == 2 && row == col){
        atomicAdd(&ws[trIdx], outr);
        atomicAdd(&ws[trIdx+1], outi);
    }
}

// ---- elementwise: C = a1*f1*X1 + a2*f2*X2 + a3*X3 + a4*X4 + g*I
// mode: 0 none; 1 f1=expm scale; 2 f1=mu,f2=1/mu; 3 f1=mu^2,f2=1/mu^2
__global__ __launch_bounds__(256) void k_combine(double* ws, int dst,
    int s1, int s2, int s3, int s4,
    double a1, double a2, double a3, double a4, double g, int mode)
{
    int ij = blockIdx.x * 256 + threadIdx.x;
    int i = ij >> 8, j = ij & 255;
    double f1 = 1.0, f2 = 1.0;
    if (mode == 1){ f1 = ws[SC_EXPM_SCALE]; }
    else if (mode == 2){ double mu = ws[SC_MU]; f1 = mu; f2 = 1.0/mu; }
    else if (mode == 3){ double mu = ws[SC_MU]; f1 = mu*mu; f2 = 1.0/(mu*mu); }
    double* C = ws + MAT0 + (size_t)dst * MATD;
    double r = 0.0, m = 0.0;
    if (s1 >= 0){ const double* X = ws + MAT0 + (size_t)s1 * MATD; r += a1*f1*X[ij]; m += a1*f1*X[NN+ij]; }
    if (s2 >= 0){ const double* X = ws + MAT0 + (size_t)s2 * MATD; r += a2*f2*X[ij]; m += a2*f2*X[NN+ij]; }
    if (s3 >= 0){ const double* X = ws + MAT0 + (size_t)s3 * MATD; r += a3*X[ij]; m += a3*X[NN+ij]; }
    if (s4 >= 0){ const double* X = ws + MAT0 + (size_t)s4 * MATD; r += a4*X[ij]; m += a4*X[NN+ij]; }
    if (i == j) r += g;
    C[ij] = r; C[NN + ij] = m;
}

__global__ void k_expm_prep(double* ws)
{
    if (threadIdx.x == 0 && blockIdx.x == 0){
        double n1 = ws[8];
        int s = 0;
        if (n1 > 0.5){
            s = (int)ceil(log2(n1 / 0.5));
            if (s < 0) s = 0; if (s > 10) s = 10;
        }
        ws[SC_EXPM_S] = (double)s;
        ws[SC_EXPM_SCALE] = ldexp(1.0, -s);
    }
}

__global__ void k_mu(double* ws)
{
    double nm = ws[8] * ws[9], nim = ws[10] * ws[11];
    double mu = pow(nim / nm, 0.125);
    if (!(mu > 0.125)) mu = 0.125;
    if (mu > 8.0) mu = 8.0;
    ws[SC_MU] = mu;
}

// S = 128 * conj(LAT - LAT^T)   (6 sqrt stages: log = 2*64*artanh)
__global__ __launch_bounds__(256) void k_build_S(double* ws)
{
    int ij = blockIdx.x * 256 + threadIdx.x;
    int i = ij >> 8, j = ij & 255;
    const double* L = ws + MAT0 + (size_t)S_LAT * MATD;
    double* S = ws + MAT0 + (size_t)PBASE * MATD;
    S[ij]      =  128.0 * (L[ij] - L[j*256 + i]);
    S[NN + ij] = -128.0 * (L[NN + ij] - L[NN + j*256 + i]);
}

// theta per u (rigorous upper bound); theta>4 -> scaling+squaring pool
__global__ __launch_bounds__(256) void k_theta_pool(double* ws)
{
    __shared__ double th[256]; __shared__ int rk[256];
    int t = threadIdx.x;
    double nS = ws[SC_NORMS2];
    double cr = ws[W_C_RE + t], ci = ws[W_C_IM + t];
    th[t] = sqrt(cr*cr + ci*ci) * nS;
    __syncthreads();
    int r = 0;
    for (int v = 0; v < 256; v++){
        if (th[v] > th[t] || (th[v] == th[t] && v < t)) r++;
    }
    rk[t] = r;
    __syncthreads();
    if (t == 0){
        int cnt = 0;
        for (int u = 0; u < 256; u++){
            double s = 0.0; int slot = -1;
            if (th[u] > 4.0 && rk[u] < NPOOL){
                double e = ceil(log2(th[u] / 4.0));
                if (e < 1.0) e = 1.0; if (e > 12.0) e = 12.0;
                s = e; slot = cnt;
                ws[W_SLOTU + cnt] = (double)u;
                cnt++;
            }
            ws[W_SU + u] = s;
            ws[W_SLOT + u] = (double)slot;
        }
        for (int k = cnt; k < NPOOL; k++) ws[W_SLOTU + k] = -1.0;
    }
}

// weights w[u][k] = (c_u / 2^{s_u})^k / k!
__global__ __launch_bounds__(256) void k_weights(double* ws)
{
    int u = threadIdx.x;
    double sc = ldexp(1.0, -(int)ws[W_SU + u]);
    double cr = ws[W_C_RE + u] * sc, ci = ws[W_C_IM + u] * sc;
    double wr = 1.0, wi = 0.0;
    ws[W_W + (u*33)*2] = 1.0; ws[W_W + (u*33)*2 + 1] = 0.0;
    for (int k = 1; k <= 32; k++){
        double inv = 1.0 / (double)k;
        double nr = (wr*cr - wi*ci) * inv, ni = (wr*ci + wi*cr) * inv;
        wr = nr; wi = ni;
        ws[W_W + (u*33 + k)*2] = wr;
        ws[W_W + (u*33 + k)*2 + 1] = wi;
    }
}

// exp_tens[u] = sum_k w[u][k] S^k -> f32 out (non-pooled, pass 0) or fp64 pool base
__global__ __launch_bounds__(256) void k_combo(double* ws, float* out, long off_ex, int f,
                                               int pass, int K)
{
    __shared__ double wre[16][33], wim[16][33];
    __shared__ int anywork;
    int t = threadIdx.x;
    int row = blockIdx.x, ug = blockIdx.y;
    if (t == 0) anywork = (pass == 0) ? 1 : 0;
    __syncthreads();
    if (pass > 0 && t < 16){
        int u = ug*16 + t;
        int slot = (int)ws[W_SLOT + u];
        int phys = slot - pass * K;
        if (slot >= 0 && phys >= 0 && phys < K) anywork = 1;
    }
    __syncthreads();
    if (!anywork) return;
    for (int i = t; i < 16*33; i += 256){
        int g = i / 33, k = i % 33;
        int u = ug*16 + g;
        wre[g][k] = ws[W_W + (u*33 + k)*2];
        wim[g][k] = ws[W_W + (u*33 + k)*2 + 1];
    }
    __syncthreads();
    int j = t, ij = row*256 + j;
    double ar[16], ai[16];
    #pragma unroll
    for (int g = 0; g < 16; g++){
        ar[g] = (row == j) ? wre[g][0] : 0.0;
        ai[g] = (row == j) ? wim[g][0] : 0.0;
    }
    for (int k = 1; k <= 32; k++){
        const double* SP = ws + MAT0 + (size_t)(PBASE + k - 1) * MATD;
        double sre = SP[ij], sim = SP[NN + ij];
        #pragma unroll
        for (int g = 0; g < 16; g++){
            ar[g] += wre[g][k]*sre - wim[g][k]*sim;
            ai[g] += wre[g][k]*sim + wim[g][k]*sre;
        }
    }
    for (int g = 0; g < 16; g++){
        int u = ug*16 + g;
        int slot = (int)ws[W_SLOT + u];
        if (slot >= 0){
            int phys = slot - pass * K;
            if (phys >= 0 && phys < K){
                double* P = ws + MAT0 + (size_t)(POOL0 + phys) * MATD;
                P[ij] = ar[g]; P[NN + ij] = ai[g];
            }
        } else if (pass == 0){
            long base = off_ex + (long)u * NN * f + (long)ij * f;
            out[base] = (float)ar[g];
            if (f == 2) out[base + 1] = (float)ai[g];
        }
    }
}

// pool squaring: virtual slot = pass*K + z; square only if round <= s_u
__global__ __launch_bounds__(256) void k_pool_sq(double* ws, int round, int pass, int K)
{
    int z = blockIdx.z;
    int vs = pass * K + z;
    int u = (vs < NPOOL) ? (int)ws[W_SLOTU + vs] : -1;
    if (u < 0) return;
    if (round > (int)ws[W_SU + u]) return;
    const double* A = ws + MAT0 + (size_t)(POOL0 + ((round & 1) ? 0 : K) + z) * MATD;
    double* C = ws + MAT0 + (size_t)(POOL0 + ((round & 1) ? K : 0) + z) * MATD;
    int tx = threadIdx.x & 15, ty = threadIdx.x >> 4;
    int row = blockIdx.y*16 + ty, col = blockIdx.x*16 + tx;
    __shared__ double Asr[16][17], Asi[16][17], Bsr[16][17], Bsi[16][17];
    double cr = 0.0, ci = 0.0;
    for (int k0 = 0; k0 < 256; k0 += 16){
        Asr[ty][tx] = A[row*256 + k0 + tx];
        Asi[ty][tx] = A[NN + row*256 + k0 + tx];
        Bsr[ty][tx] = A[(k0 + ty)*256 + col];
        Bsi[ty][tx] = A[NN + (k0 + ty)*256 + col];
        __syncthreads();
        #pragma unroll
        for (int kk = 0; kk < 16; kk++){
            double xr = Asr[ty][kk], xi = Asi[ty][kk];
            double yr = Bsr[kk][tx], yi = Bsi[kk][tx];
            cr += xr*yr - xi*yi;
            ci += xr*yi + xi*yr;
        }
        __syncthreads();
    }
    C[row*256 + col] = cr;
    C[NN + row*256 + col] = ci;
}

__global__ __launch_bounds__(256) void k_pool_out(const double* ws, float* out, long off_ex,
                                                  int f, int pass, int K)
{
    int z = blockIdx.y;
    int vs = pass * K + z;
    int u = (vs < NPOOL) ? (int)ws[W_SLOTU + vs] : -1;
    if (u < 0) return;
    int su = (int)ws[W_SU + u];
    int ij = blockIdx.x * 256 + threadIdx.x;
    const double* P = ws + MAT0 + (size_t)(POOL0 + ((su & 1) ? K : 0) + z) * MATD;
    long base = off_ex + (long)u * NN * f + (long)ij * f;
    out[base] = (float)P[ij];
    if (f == 2) out[base + 1] = (float)P[NN + ij];
}

__global__ __launch_bounds__(256) void k_cast_out(const double* ws, int slot, float* out, long off, int f)
{
    int ij = blockIdx.x * 256 + threadIdx.x;
    const double* P = ws + MAT0 + (size_t)slot * MATD;
    out[off + (long)ij * f] = (float)P[ij];
    if (f == 2) out[off + (long)ij * f + 1] = (float)P[NN + ij];
}

// ============================ host ============================
extern "C" void kernel_launch(void* const* d_in, const int* in_sizes, int n_in,
                              void* d_out, int out_size, void* d_ws, size_t ws_size,
                              hipStream_t stream)
{
    double* ws = (double*)d_ws;
    float* out = (float*)d_out;

    int f = (out_size >= 33816832) ? 2 : 1;
    long off_ex = 256;
    long off_uw = off_ex + (long)f * 16777216L;
    long off_ew = off_uw + (long)f * 65536L;

    k_init<<<128, 256, 0, stream>>>(ws);
    k_detect<<<1, 64, 0, stream>>>(d_in[0], ws);
    k_small<<<1, 256, 0, stream>>>(d_in[0], d_in[1], d_in[2], d_in[3], d_in[4], ws, out);

    long slotsAvail = (long)(ws_size / 8 - MAT0) / MATD;
    if (slotsAvail < POOL0 + 32) return;   // need >= 52 work slots + 16x2 pool (~88.3 MB)
    int K = (int)((slotsAvail - POOL0) / 2);
    if (K > NPOOL) K = NPOOL;
    if (K < 16) K = 16;
    int P = (NPOOL + K - 1) / K;

    auto MP = [&](int s){ return ws + MAT0 + (size_t)s * MATD; };
    auto ZG = [&](int a, int b, int c, int preA, int preB, double al, double be,
                  int d, double ga, int fm, int round, int flagIdx, int trIdx){
        k_zgemm<<<dim3(16,16,1), 256, 0, stream>>>(MP(a), MP(b), MP(c),
            d >= 0 ? MP(d) : nullptr, preA, preB, al, be, ga, ws,
            fm, round, flagIdx, trIdx, 0L, 0L, 0L);
    };
    auto GEMM = [&](int a, int b, int c, int preA, int preB, double al, double be, int d, double ga){
        ZG(a, b, c, preA, preB, al, be, d, ga, 0, 0, 0, 0);
    };
    auto COPY = [&](int dst, int src){
        k_combine<<<256, 256, 0, stream>>>(ws, dst, src, -1, -1, -1, 1.0, 0, 0, 0, 0.0, 0);
    };

    int invid = 0;
    // NS inverse: dst = src^-1. Cold start X0 = src^H/(n1*ninf); trace-gated early exit.
    auto INV = [&](int src, int dst, int maxit){
        k_norm1inf<<<1, 256, 0, stream>>>(MP(src), ws, 8);
        k_txconj<<<256, 256, 0, stream>>>(ws, S_X, src);
        int xc = S_X, xo = S_X2;
        int flagIdx = FLAGBASE + invid;
        for (int i = 0; i < maxit; i++){
            int trIdx = TRBASE + invid*96 + 2*i;
            ZG(src, xc, S_T, 0, 0, 1.0, 0.0, -1, 0.0, 2, 0, flagIdx, trIdx);  // T = M X (+trace)
            ZG(xc, S_T, xo, 0, 1, 1.0, 0.0, -1, 0.0, 3, 0, flagIdx, trIdx);   // X' = X(2I-T)
            int tmp = xc; xc = xo; xo = tmp;
        }
        COPY(dst, xc);   // maxit even -> xc == S_X
        invid++;
    };

    k_build_mats<<<256, 256, 0, stream>>>(d_in[5], d_in[6], d_in[7], d_in[8], ws);
    k_cast_out<<<256, 256, 0, stream>>>(ws, S_NUW, out, off_uw, f);

    // -------- expm(new_uw): scaling + Paterson-Stockmeyer deg-16 Taylor + squarings ----
    static const double INVF[17] = {
        1.0, 1.0, 0.5, 1.0/6.0, 1.0/24.0, 1.0/120.0, 1.0/720.0, 1.0/5040.0,
        1.0/40320.0, 1.0/362880.0, 1.0/3628800.0, 1.0/39916800.0, 1.0/479001600.0,
        1.0/6227020800.0, 1.0/87178291200.0, 1.0/1307674368000.0, 1.0/20922789888000.0 };
    k_norm1inf<<<1, 256, 0, stream>>>(MP(S_NUW), ws, 8);
    k_expm_prep<<<1, 64, 0, stream>>>(ws);
    k_combine<<<256, 256, 0, stream>>>(ws, S_LAT, S_NUW, -1, -1, -1, 1.0, 0, 0, 0, 0.0, 1); // T = 2^-s NUW
    GEMM(S_LAT, S_LAT, S_T2, 0, 0, 1.0, 0.0, -1, 0.0);
    GEMM(S_T2, S_LAT, S_T3, 0, 0, 1.0, 0.0, -1, 0.0);
    GEMM(S_T2, S_T2, S_T4, 0, 0, 1.0, 0.0, -1, 0.0);
    k_combine<<<256, 256, 0, stream>>>(ws, S_E1, -1, -1, -1, -1, 0, 0, 0, 0, INVF[16], 0);
    for (int b = 3; b >= 0; b--){
        GEMM(S_T4, S_E1, S_E2, 0, 0, 1.0, 0.0, -1, 0.0);
        k_combine<<<256, 256, 0, stream>>>(ws, S_E1, S_E2, S_LAT, S_T2, S_T3,
            1.0, INVF[4*b+1], INVF[4*b+2], INVF[4*b+3], INVF[4*b], 0);
    }
    for (int r = 1; r <= 10; r++){
        int src = (r & 1) ? S_E1 : S_E2, dst = (r & 1) ? S_E2 : S_E1;
        ZG(src, src, dst, 0, 0, 1.0, 0.0, -1, 0.0, 1, r, 0, 0);
    }
    GEMM(S_EW, S_E1, S_M2, 1, 0, 1.0, 0.0, -1, 0.0);   // new_Ew = conj(Ew) expm(new_uw)
    k_cast_out<<<256, 256, 0, stream>>>(ws, S_M2, out, off_ew, f);

    // -------- logm(Ew): 6 scaled product-form DB sqrt stages, Cayley + artanh(deg39) ----
    auto SQRT_STAGE = [&](int aSlot, int iters, int nsmax) -> int {
        COPY(S_M, aSlot); COPY(S_Y, aSlot);
        int mc = S_M, mo = S_M2, yc = S_Y, yo = S_Y2;
        for (int it = 0; it < iters; it++){
            INV(mc, S_IY, nsmax);                                   // writes ws[8,9] for M
            k_norm1inf<<<1, 256, 0, stream>>>(MP(S_IY), ws, 10);    // ws[10,11] for M^-1
            k_mu<<<1, 1, 0, stream>>>(ws);
            k_combine<<<256, 256, 0, stream>>>(ws, mo, mc, S_IY, -1, -1,
                0.25, 0.25, 0, 0, 0.5, 3);
            GEMM(yc, S_IY, S_G, 0, 0, 1.0, 0.0, -1, 0.0);
            k_combine<<<256, 256, 0, stream>>>(ws, yo, yc, S_G, -1, -1,
                0.5, 0.5, 0, 0, 0.0, 2);
            int t1 = mc; mc = mo; mo = t1;
            int t2 = yc; yc = yo; yo = t2;
        }
        return yc;
    };

    static const int DB_IT[6] = {22, 12, 10, 10, 8, 8};
    static const int NS_IT[6] = {44, 24, 20, 18, 16, 16};
    int bcur = S_EW;
    for (int st = 0; st < 6; st++)
        bcur = SQRT_STAGE(bcur, DB_IT[st], NS_IT[st]);   // bcur = Ew^(1/64)

    // Cayley: W = (B-I)(B+I)^-1
    k_combine<<<256, 256, 0, stream>>>(ws, S_M, bcur, -1, -1, -1, 1.0, 0, 0, 0, 1.0, 0);
    INV(S_M, S_IY, 20);
    GEMM(bcur, S_IY, S_W, 2, 0, 1.0, 0.0, -1, 0.0);
    GEMM(S_W, S_W, S_V, 0, 0, 1.0, 0.0, -1, 0.0);
    // artanh(W) = W * P(V), P = sum_{j=0}^{19} V^j/(2j+1)  (deg-39 odd series)
    k_combine<<<256, 256, 0, stream>>>(ws, S_G, -1, -1, -1, -1, 0, 0, 0, 0, 1.0/39.0, 0);
    {
        int gc = S_G, go = S_G2;
        for (int j = 18; j >= 0; j--){
            GEMM(S_V, gc, go, 0, 0, 1.0, 0.0, -1, 1.0/(double)(2*j + 1));
            int tmp = gc; gc = go; go = tmp;
        }
        GEMM(S_W, gc, S_LAT, 0, 0, 1.0, 0.0, -1, 0.0);  // LAT = artanh(W); L = 128*LAT
    }
    k_build_S<<<256, 256, 0, stream>>>(ws);             // S^1 at PBASE

    // -------- batched exp_tens = expm(c_u S): shared powers + pooled squaring --------
    k_norm1inf<<<1, 256, 0, stream>>>(MP(PBASE), ws, 12);   // rigorous norm bound inputs
    k_fro<<<1, 256, 0, stream>>>(MP(PBASE), ws);
    k_snorm<<<1, 1, 0, stream>>>(ws);
    k_theta_pool<<<1, 256, 0, stream>>>(ws);
    k_weights<<<1, 256, 0, stream>>>(ws);
    for (int m = 1; m < 32; m *= 2){
        int cnt = (m < 32 - m) ? m : (32 - m);
        k_zgemm<<<dim3(16,16,cnt), 256, 0, stream>>>(MP(PBASE + m - 1), MP(PBASE), MP(PBASE + m),
            nullptr, 0, 0, 1.0, 0.0, 0.0, ws, 0, 0, 0, 0, 0L, MATD, MATD);
    }
    for (int p = 0; p < P; p++){
        k_combo<<<dim3(256,16), 256, 0, stream>>>(ws, out, off_ex, f, p, K);
        for (int r = 1; r <= 12; r++)
            k_pool_sq<<<dim3(16,16,K), 256, 0, stream>>>(ws, r, p, K);
        k_pool_out<<<dim3(256,K), 256, 0, stream>>>(ws, out, off_ex, f, p, K);
    }
}